// Round 4
// baseline (646.984 us; speedup 1.0000x reference)
//
#include <hip/hip_runtime.h>
#include <stdint.h>

#define N_NODES 20000
#define N_EDGES 100000

typedef __bf16 bf16;
typedef bf16  bf16x8 __attribute__((ext_vector_type(8)));
typedef float f32x4  __attribute__((ext_vector_type(4)));

__device__ __forceinline__ f32x4 mfma16(bf16x8 a, bf16x8 b, f32x4 c) {
  return __builtin_amdgcn_mfma_f32_16x16x32_bf16(a, b, c, 0, 0, 0);
}

__device__ __forceinline__ float silu_(float y) {
  return y / (1.0f + __expf(-y));
}

// ---- workspace layout (bytes) ----
#define OFF_W0T   0u          // [64][32]   mlp_w0/sqrt(8), K zero-padded 8->32
#define OFF_W1T   4096u       // [64][64]   mlp_w1 * SILU_NORM/8
#define OFF_W2T   12288u      // [64][64]   mlp_w2 * SILU_NORM/8
#define OFF_W3T   20480u      // [512][64]  mlp_w3 * SILU_NORM/8
#define OFF_WOS   86016u      // [128][256] W_out_s/16 * (u<128 ? PW_0E : PW_0E*INV_SQRT3)
#define OFF_WOV   151552u     // [128][256] W_out_v/16 * PW_0E   (PW_1O*INV_SQRT3 == PW_0E)
#define OFF_WST   217088u     // [128][128] W_up_s/sqrt(128)
#define OFF_WVT   249856u     // [128][128] W_up_v/sqrt(128)
#define OFF_SUP   282624u     // [20000][128] bf16 s_up
#define OFF_VUP   5402624u    // [20000][384] bf16 v_up, layout [n][i][u]
#define OFF_MID   20762624u   // [chunk_edges][4][256] bf16 (tensor-product output)

// ---------------- K0: weight prep (transpose + scale + bf16) ----------------
__global__ __launch_bounds__(256) void k0_prep(
    const float* __restrict__ wus, const float* __restrict__ wuv,
    const float* __restrict__ w0,  const float* __restrict__ w1,
    const float* __restrict__ w2,  const float* __restrict__ w3,
    const float* __restrict__ wos_g, const float* __restrict__ wov_g,
    char* __restrict__ ws) {
  const int idx = blockIdx.x * 256 + threadIdx.x;  // 0..32767
  bf16* W0T = (bf16*)(ws + OFF_W0T);
  bf16* W1T = (bf16*)(ws + OFF_W1T);
  bf16* W2T = (bf16*)(ws + OFF_W2T);
  bf16* W3T = (bf16*)(ws + OFF_W3T);
  bf16* WOS = (bf16*)(ws + OFF_WOS);
  bf16* WOV = (bf16*)(ws + OFF_WOV);
  bf16* WST = (bf16*)(ws + OFF_WST);
  bf16* WVT = (bf16*)(ws + OFF_WVT);

  const float cS   = 0.08838834764831845f;   // 1/sqrt(128)
  const float c0   = 0.35355339059327373f;   // 1/sqrt(8)
  const float c12  = 1.6790390826f / 8.0f;   // SILU_NORM/sqrt(64)
  const float cosA = 0.04419417382415922f;   // PW_0E/16
  const float cosB = 0.025515518153991442f;  // PW_0E*INV_SQRT3/16
  const float cov  = 0.04419417382415922f;   // PW_1O*INV_SQRT3/16 == PW_0E/16

  if (idx < 16384) {
    int w = idx >> 7, u = idx & 127;
    WST[idx] = (bf16)(wus[u * 128 + w] * cS);
    WVT[idx] = (bf16)(wuv[u * 128 + w] * cS);
  }
  if (idx < 2048) {
    int h = idx >> 5, r = idx & 31;
    W0T[idx] = (bf16)((r < 8) ? w0[r * 64 + h] * c0 : 0.0f);
  }
  if (idx < 4096) {
    int h = idx >> 6, k = idx & 63;
    W1T[idx] = (bf16)(w1[k * 64 + h] * c12);
    W2T[idx] = (bf16)(w2[k * 64 + h] * c12);
  }
  {
    int j = idx >> 6, k = idx & 63;
    W3T[idx] = (bf16)(w3[k * 512 + j] * c12);
    int w = idx >> 8, u = idx & 255;
    WOS[idx] = (bf16)(wos_g[u * 128 + w] * ((u < 128) ? cosA : cosB));
    WOV[idx] = (bf16)(wov_g[u * 128 + w] * cov);
  }
}

// ---------------- K1: node up-projection ----------------
__global__ __launch_bounds__(256, 4) void k1_nodeup(const float* __restrict__ nf,
                                                    char* __restrict__ ws) {
  __shared__ __align__(16) bf16 tiles[4][32 * 136];  // [stream][row][K pad 136]
  const int n0 = blockIdx.x * 32;
  const int t = threadIdx.x;

  #pragma unroll
  for (int p = 0; p < 16; p++) {
    int idx = p * 256 + t;           // 0..4095
    int r = idx >> 7, c4 = idx & 127;
    const float4 f = *(const float4*)&nf[(size_t)(n0 + r) * 512 + c4 * 4];
    float vals[4] = {f.x, f.y, f.z, f.w};
    #pragma unroll
    for (int e2 = 0; e2 < 4; e2++) {
      int g = c4 * 4 + e2;
      if (g < 128) {
        tiles[0][r * 136 + g] = (bf16)vals[e2];
      } else {
        int gg = g - 128;
        int u = gg / 3, i = gg - 3 * u;
        tiles[1 + i][r * 136 + u] = (bf16)vals[e2];
      }
    }
  }
  __syncthreads();

  const int wv = t >> 6, lane = t & 63;
  const int m = lane & 15, q = lane >> 4;
  const bf16* BT = (const bf16*)(ws + ((wv == 0) ? OFF_WST : OFF_WVT));
  const bf16* At = tiles[wv];

  const f32x4 z = {0.f, 0.f, 0.f, 0.f};
  f32x4 acc[2][8] = {{z, z, z, z, z, z, z, z}, {z, z, z, z, z, z, z, z}};
  #pragma unroll
  for (int kk = 0; kk < 128; kk += 32) {
    bf16x8 af0 = *(const bf16x8*)&At[m * 136 + kk + q * 8];
    bf16x8 af1 = *(const bf16x8*)&At[(16 + m) * 136 + kk + q * 8];
    #pragma unroll
    for (int nt = 0; nt < 8; nt++) {
      bf16x8 bfr = *(const bf16x8*)&BT[(nt * 16 + m) * 128 + kk + q * 8];
      acc[0][nt] = mfma16(af0, bfr, acc[0][nt]);
      acc[1][nt] = mfma16(af1, bfr, acc[1][nt]);
    }
  }

  bf16* sup = (bf16*)(ws + OFF_SUP);
  bf16* vup = (bf16*)(ws + OFF_VUP);
  #pragma unroll
  for (int rt = 0; rt < 2; rt++) {
    #pragma unroll
    for (int nt = 0; nt < 8; nt++) {
      int col = nt * 16 + m;
      #pragma unroll
      for (int r = 0; r < 4; r++) {
        int node = n0 + rt * 16 + q * 4 + r;
        if (wv == 0) sup[node * 128 + col] = (bf16)acc[rt][nt][r];
        else         vup[node * 384 + (wv - 1) * 128 + col] = (bf16)acc[rt][nt][r];
      }
    }
  }
}

// ---------------- K23a: edge MLP + tensor product -> mid ----------------
// 32 edges/block, 4 waves. MLP as before (5 barriers), then the TP as a pure
// elementwise phase: thread (e=t>>3, uc=t&7) gathers sup/vup chunks directly
// from global (8 threads/edge read contiguous 256B), multiplies with tpw from
// LDS, writes mid[e][st][256] bf16. No out-projection here.
#define TPW_LD 520
// LDS: tpw 32x520 (33280) + h0 32x72 (4608) + h1 32x72 (4608) = 42496 B
__global__ __launch_bounds__(256, 3) void k23a_mlp_tp(
    const float* __restrict__ efeat, const float* __restrict__ attrs,
    const int* __restrict__ sender, char* __restrict__ ws, int ebase) {
  __shared__ __align__(16) bf16 tpw[32 * TPW_LD];
  __shared__ __align__(16) bf16 h0[32 * 72];
  __shared__ __align__(16) bf16 h1[32 * 72];

  const int e0l = blockIdx.x * 32;          // chunk-local edge base
  const int e0g = ebase + e0l;              // global edge base
  const int t = threadIdx.x;
  const int wv = t >> 6, lane = t & 63;
  const int m = lane & 15, q = lane >> 4;
  const f32x4 z = {0.f, 0.f, 0.f, 0.f};

  const bf16* W0T = (const bf16*)(ws + OFF_W0T);
  const bf16* W1T = (const bf16*)(ws + OFF_W1T);
  const bf16* W2T = (const bf16*)(ws + OFF_W2T);
  const bf16* W3T = (const bf16*)(ws + OFF_W3T);

  const int rt = wv & 1, nh = wv >> 1;      // row-tile of 16, N-half

  { // layer 0: efeat (32x8, zero-padded K=32) @ W0T -> h0 (A built in-reg)
    bf16x8 af;
    #pragma unroll
    for (int j = 0; j < 8; j++) af[j] = (bf16)0.0f;
    if (q == 0) {
      const float4* ef4 = (const float4*)efeat;
      float4 u0 = ef4[(size_t)(e0g + rt * 16 + m) * 2 + 0];
      float4 u1 = ef4[(size_t)(e0g + rt * 16 + m) * 2 + 1];
      af[0] = (bf16)u0.x; af[1] = (bf16)u0.y; af[2] = (bf16)u0.z; af[3] = (bf16)u0.w;
      af[4] = (bf16)u1.x; af[5] = (bf16)u1.y; af[6] = (bf16)u1.z; af[7] = (bf16)u1.w;
    }
    f32x4 acc[2] = {z, z};
    #pragma unroll
    for (int ntl = 0; ntl < 2; ntl++) {
      bf16x8 bfr = *(const bf16x8*)&W0T[((nh * 2 + ntl) * 16 + m) * 32 + q * 8];
      acc[ntl] = mfma16(af, bfr, acc[ntl]);
    }
    #pragma unroll
    for (int ntl = 0; ntl < 2; ntl++)
      #pragma unroll
      for (int r = 0; r < 4; r++)
        h0[(rt * 16 + q * 4 + r) * 72 + (nh * 2 + ntl) * 16 + m] = (bf16)silu_(acc[ntl][r]);
  }
  __syncthreads();  // B1

  { // layer 1: h0 @ W1T -> h1
    f32x4 acc[2] = {z, z};
    #pragma unroll
    for (int kk = 0; kk < 64; kk += 32) {
      bf16x8 af = *(const bf16x8*)&h0[(rt * 16 + m) * 72 + kk + q * 8];
      #pragma unroll
      for (int ntl = 0; ntl < 2; ntl++) {
        bf16x8 bfr = *(const bf16x8*)&W1T[((nh * 2 + ntl) * 16 + m) * 64 + kk + q * 8];
        acc[ntl] = mfma16(af, bfr, acc[ntl]);
      }
    }
    #pragma unroll
    for (int ntl = 0; ntl < 2; ntl++)
      #pragma unroll
      for (int r = 0; r < 4; r++)
        h1[(rt * 16 + q * 4 + r) * 72 + (nh * 2 + ntl) * 16 + m] = (bf16)silu_(acc[ntl][r]);
  }
  __syncthreads();  // B2

  { // layer 2: h1 @ W2T -> h0
    f32x4 acc[2] = {z, z};
    #pragma unroll
    for (int kk = 0; kk < 64; kk += 32) {
      bf16x8 af = *(const bf16x8*)&h1[(rt * 16 + m) * 72 + kk + q * 8];
      #pragma unroll
      for (int ntl = 0; ntl < 2; ntl++) {
        bf16x8 bfr = *(const bf16x8*)&W2T[((nh * 2 + ntl) * 16 + m) * 64 + kk + q * 8];
        acc[ntl] = mfma16(af, bfr, acc[ntl]);
      }
    }
    __syncthreads();  // h1 reads done; h0's layer-1 readers passed B2
    #pragma unroll
    for (int ntl = 0; ntl < 2; ntl++)
      #pragma unroll
      for (int r = 0; r < 4; r++)
        h0[(rt * 16 + q * 4 + r) * 72 + (nh * 2 + ntl) * 16 + m] = (bf16)silu_(acc[ntl][r]);
  }
  __syncthreads();  // B3: h0 final ready

  { // layer 3: h0 @ W3T -> tpw (full 512 cols)
    bf16x8 hf0 = *(const bf16x8*)&h0[(rt * 16 + m) * 72 + 0  + q * 8];
    bf16x8 hf1 = *(const bf16x8*)&h0[(rt * 16 + m) * 72 + 32 + q * 8];
    #pragma unroll 4
    for (int i = 0; i < 16; i++) {
      int ntg = nh * 16 + i;
      f32x4 a3 = z;
      const bf16* wb = &W3T[(size_t)(ntg * 16 + m) * 64 + q * 8];
      bf16x8 b0 = *(const bf16x8*)&wb[0];
      bf16x8 b1 = *(const bf16x8*)&wb[32];
      a3 = mfma16(hf0, b0, a3);
      a3 = mfma16(hf1, b1, a3);
      #pragma unroll
      for (int r = 0; r < 4; r++)
        tpw[(rt * 16 + q * 4 + r) * TPW_LD + ntg * 16 + m] = (bf16)a3[r];
    }
  }
  __syncthreads();  // B4: tpw ready

  // ---- tensor product, pure elementwise: thread = (edge, 16-u chunk) ----
  const int e  = t >> 3;                    // 0..31 local edge
  const int uc = t & 7;                     // 16-col chunk
  const int se = sender[e0g + e];
  const float4 at = ((const float4*)attrs)[e0g + e];
  const bf16* tpr  = tpw + e * TPW_LD;
  const bf16* supR = (const bf16*)(ws + OFF_SUP) + (size_t)se * 128;
  const bf16* vupR = (const bf16*)(ws + OFF_VUP) + (size_t)se * 384;
  bf16* midp = (bf16*)(ws + OFF_MID) + (size_t)(e0l + e) * 1024;

  #pragma unroll
  for (int c = 0; c < 2; c++) {
    const int u0 = uc * 16 + c * 8;
    bf16x8 w00 = *(const bf16x8*)&tpr[u0];
    bf16x8 w01 = *(const bf16x8*)&tpr[128 + u0];
    bf16x8 w10 = *(const bf16x8*)&tpr[256 + u0];
    bf16x8 w11 = *(const bf16x8*)&tpr[384 + u0];
    bf16x8 sv = *(const bf16x8*)&supR[u0];
    bf16x8 vx = *(const bf16x8*)&vupR[u0];
    bf16x8 vy = *(const bf16x8*)&vupR[128 + u0];
    bf16x8 vz = *(const bf16x8*)&vupR[256 + u0];
    bf16x8 osa, osb, ova0, ovb0, ova1, ovb1, ova2, ovb2;
    #pragma unroll
    for (int j = 0; j < 8; j++) {
      float fw00 = (float)w00[j], fw01 = (float)w01[j];
      float fw10 = (float)w10[j], fw11 = (float)w11[j];
      float fsv = (float)sv[j];
      float fvx = (float)vx[j], fvy = (float)vy[j], fvz = (float)vz[j];
      osa[j]  = (bf16)(fw00 * fsv * at.x);                         // a0
      osb[j]  = (bf16)(fw11 * (fvx * at.y + fvy * at.z + fvz * at.w)); // b0
      ova0[j] = (bf16)(fw01 * fsv * at.y);                         // a1_x
      ova1[j] = (bf16)(fw01 * fsv * at.z);                         // a1_y
      ova2[j] = (bf16)(fw01 * fsv * at.w);                         // a1_z
      ovb0[j] = (bf16)(fw10 * at.x * fvx);                         // b1_x
      ovb1[j] = (bf16)(fw10 * at.x * fvy);                         // b1_y
      ovb2[j] = (bf16)(fw10 * at.x * fvz);                         // b1_z
    }
    *(bf16x8*)&midp[u0]             = osa;
    *(bf16x8*)&midp[128 + u0]       = osb;
    *(bf16x8*)&midp[256 + u0]       = ova0;
    *(bf16x8*)&midp[256 + 128 + u0] = ovb0;
    *(bf16x8*)&midp[512 + u0]       = ova1;
    *(bf16x8*)&midp[512 + 128 + u0] = ovb1;
    *(bf16x8*)&midp[768 + u0]       = ova2;
    *(bf16x8*)&midp[768 + 128 + u0] = ovb2;
  }
}

// ---------------- K23b: out-projection GEMM ----------------
// grid (ceil(ec/64), 4 streams). Per block: stage A-tile 64x256 bf16 into LDS
// (global_load_lds, pre-swizzled src so ds_read is conflict-free), then
// K=256 GEMM vs WOS/WOV streamed from L2 (same lines for all blocks of a
// stream -> hot). One barrier per block.
#define GLOAD_LDS16(gsrc, ldst) __builtin_amdgcn_global_load_lds( \
    (const __attribute__((address_space(1))) void*)(gsrc),        \
    (__attribute__((address_space(3))) void*)(ldst), 16, 0, 0)

__global__ __launch_bounds__(256, 3) void k23b_out(
    const char* __restrict__ ws, float* __restrict__ out,
    int ebase, int ecount) {
  __shared__ __align__(16) bf16 Als[64 * 256];   // 32768 B
  const int st = blockIdx.y;                      // 0=s, 1..3=v_xyz
  const int r0 = blockIdx.x * 64;                 // chunk-local edge base
  const int t = threadIdx.x;
  const int wv = t >> 6, lane = t & 63;
  const int m = lane & 15, q = lane >> 4;
  const f32x4 z = {0.f, 0.f, 0.f, 0.f};

  const char* mid = ws + OFF_MID;

  // stage A: 2048 x 16B chunks, linear LDS dest, swizzled global src
  #pragma unroll
  for (int j = 0; j < 8; j++) {
    int g = (j * 4 + wv) * 64 + lane;             // 0..2047
    int r = g >> 5, c5 = g & 31;                  // row, 16B-chunk in row
    int er = r0 + r; if (er >= ecount) er = ecount - 1;
    int cs = (c5 & ~7) | ((c5 ^ (r & 7)) & 7);    // inverse swizzle on src
    GLOAD_LDS16(mid + (size_t)er * 2048 + (size_t)st * 512 + cs * 16,
                (char*)Als + (size_t)((j * 4 + wv) * 64) * 16);
  }
  __syncthreads();   // drains the DMA

  const bf16* WB = (const bf16*)(ws + ((st == 0) ? OFF_WOS : OFF_WOV));
  const int R = wv * 16 + m;                      // A row this lane reads
  const int rsw = R & 7;

  f32x4 acc[8] = {z, z, z, z, z, z, z, z};
  #pragma unroll
  for (int kk8 = 0; kk8 < 8; kk8++) {             // K step 32
    const int kk = kk8 * 32;
    const int cl = kk8 * 4 + q;                   // logical 16B chunk 0..31
    const int cp = (cl & ~7) | ((cl ^ rsw) & 7);  // swizzled
    bf16x8 af = *(const bf16x8*)&Als[R * 256 + cp * 8];
    #pragma unroll
    for (int nt = 0; nt < 8; nt++) {
      bf16x8 bfr = *(const bf16x8*)&WB[(size_t)(nt * 16 + m) * 256 + kk + q * 8];
      acc[nt] = mfma16(af, bfr, acc[nt]);
    }
  }

  // epilogue: D row = wv*16 + q*4 + r (edge), col = nt*16+m
  #pragma unroll
  for (int nt = 0; nt < 8; nt++) {
    int col = nt * 16 + m;
    #pragma unroll
    for (int r = 0; r < 4; r++) {
      int le = r0 + wv * 16 + q * 4 + r;
      if (le < ecount) {
        float v = acc[nt][r];
        size_t row = (size_t)(ebase + le) * 512;
        if (st == 0) out[row + col] = v;                       // out_s
        else         out[row + 128 + 3 * col + (st - 1)] = v;  // out_v
      }
    }
  }
}

extern "C" void kernel_launch(void* const* d_in, const int* in_sizes, int n_in,
                              void* d_out, int out_size, void* d_ws, size_t ws_size,
                              hipStream_t stream) {
  const float* node_feats = (const float*)d_in[0];
  const float* edge_attrs = (const float*)d_in[1];
  const float* edge_feats = (const float*)d_in[2];
  const int*   edge_index = (const int*)d_in[3];
  const float* W_up_s = (const float*)d_in[4];
  const float* W_up_v = (const float*)d_in[5];
  const float* w0 = (const float*)d_in[6];
  const float* w1 = (const float*)d_in[7];
  const float* w2 = (const float*)d_in[8];
  const float* w3 = (const float*)d_in[9];
  const float* Wos = (const float*)d_in[10];
  const float* Wov = (const float*)d_in[11];
  float* out = (float*)d_out;
  char* ws = (char*)d_ws;

  k0_prep<<<dim3(128), dim3(256), 0, stream>>>(W_up_s, W_up_v, w0, w1, w2, w3,
                                               Wos, Wov, ws);
  k1_nodeup<<<dim3(625), dim3(256), 0, stream>>>(node_feats, ws);

  // chunk edges so mid fits in the workspace tail
  long cap = (ws_size > (size_t)OFF_MID) ? (long)(ws_size - OFF_MID) : 0;
  long epc = (cap / 2048) & ~31L;          // edges per chunk, multiple of 32
  if (epc > N_EDGES) epc = N_EDGES;
  if (epc < 32) epc = 32;                  // ws too small would be fatal anyway
  for (long eb = 0; eb < N_EDGES; eb += epc) {
    long ec = N_EDGES - eb; if (ec > epc) ec = epc;
    k23a_mlp_tp<<<dim3((unsigned)(ec / 32)), dim3(256), 0, stream>>>(
        edge_feats, edge_attrs, edge_index, ws, (int)eb);
    k23b_out<<<dim3((unsigned)((ec + 63) / 64), 4), dim3(256), 0, stream>>>(
        ws, out, (int)eb, (int)ec);
  }
}